// Round 1
// baseline (339.886 us; speedup 1.0000x reference)
//
#include <hip/hip_runtime.h>
#include <math.h>

#define NEG 0.2f

typedef short bf16x8 __attribute__((ext_vector_type(8)));
typedef float f32x4  __attribute__((ext_vector_type(4)));
typedef float f32x2  __attribute__((ext_vector_type(2)));

// ---------------------------------------------------------------------------
// helpers
// ---------------------------------------------------------------------------
static __device__ __forceinline__ f32x2 pkfma(f32x2 a, f32x2 b, f32x2 c) {
    return __builtin_elementwise_fma(a, b, c);   // -> v_pk_fma_f32
}
static __device__ __forceinline__ f32x2 splat2(float x) { return (f32x2){x, x}; }

static __device__ __forceinline__ unsigned short f2bf(float f) {   // RNE, finite
    unsigned int x = __float_as_uint(f);
    unsigned int r = (x + 0x7FFFu + ((x >> 16) & 1u)) >> 16;
    return (unsigned short)r;
}
static __device__ __forceinline__ float rlane(float v, int l) {
    return __int_as_float(__builtin_amdgcn_readlane(__float_as_int(v), l));
}

// Sum across each 16-lane DPP row (head h = lanes 16h..16h+15).
#define DPP_ADD(x, ctrl) \
    ((x) + __int_as_float(__builtin_amdgcn_update_dpp( \
        __float_as_int(x), __float_as_int(x), (ctrl), 0xF, 0xF, true)))
static __device__ __forceinline__ float rowsum16(float v) {
    v = DPP_ADD(v, 0xB1);   // quad_perm xor1
    v = DPP_ADD(v, 0x4E);   // quad_perm xor2
    v = DPP_ADD(v, 0x141);  // row_half_mirror
    v = DPP_ADD(v, 0x140);  // row_mirror
    return v;
}

// ---------------------------------------------------------------------------
// CSR build + W_aggr transpose + fs precompute (fs = x_src @ Ws + bs, bf16).
// fs precompute: one node per wave, lanes span the 256 output feats (4/lane).
// Amortizes the 16-pkfma GEMV once per SOURCE NODE instead of once per EDGE
// (3.2x redundancy removed from the k_gat hot loop).
// ---------------------------------------------------------------------------
__global__ void k_hist_wt_fs(
    const int* __restrict__ dst_s, int Es, const int* __restrict__ dst_n, int En,
    int* __restrict__ deg_s, int* __restrict__ deg_n,
    const float* __restrict__ W, unsigned short* __restrict__ Wt,
    const float* __restrict__ x_s, const float* __restrict__ Ws_s,
    const float* __restrict__ bs_s, unsigned short* __restrict__ fs_s, int Ns,
    const float* __restrict__ x_n, const float* __restrict__ Ws_n,
    const float* __restrict__ bs_n, unsigned short* __restrict__ fs_n, int Nn)
{
    int i = blockIdx.x * 256 + threadIdx.x;
    if (i < Es) atomicAdd(&deg_s[dst_s[i]], 1);
    int j = i - Es;
    if (j >= 0 && j < En) atomicAdd(&deg_n[dst_n[j]], 1);
    if (i < 512 * 256) {                 // W[512][256] f32 -> Wt[256][512] bf16
        int k = i >> 8, n = i & 255;
        Wt[(size_t)n * 512 + k] = f2bf(W[i]);
    }

    // ---- fs = x @ Ws + bs, one node per wave
    int wv = i >> 6, lane = i & 63;
    const float *x, *Ws, *bs; unsigned short* fs; int node;
    if (wv < Ns)           { x = x_s; Ws = Ws_s; bs = bs_s; fs = fs_s; node = wv; }
    else if (wv < Ns + Nn) { x = x_n; Ws = Ws_n; bs = bs_n; fs = fs_n; node = wv - Ns; }
    else return;

    const int d0 = lane * 4;
    float4 b4 = *(const float4*)&bs[d0];
    f32x2 a01 = {b4.x, b4.y}, a23 = {b4.z, b4.w};
    float4 xa = *(const float4*)&x[(size_t)node * 8];      // broadcast loads
    float4 xb = *(const float4*)&x[(size_t)node * 8 + 4];
    float xs[8] = {xa.x, xa.y, xa.z, xa.w, xb.x, xb.y, xb.z, xb.w};
#pragma unroll
    for (int k = 0; k < 8; ++k) {
        float4 w = *(const float4*)&Ws[k * 256 + d0];
        f32x2 xk = splat2(xs[k]);
        a01 = pkfma(xk, (f32x2){w.x, w.y}, a01);
        a23 = pkfma(xk, (f32x2){w.z, w.w}, a23);
    }
    ushort4 o;
    o.x = f2bf(a01.x); o.y = f2bf(a01.y); o.z = f2bf(a23.x); o.w = f2bf(a23.y);
    *(ushort4*)&fs[(size_t)node * 256 + d0] = o;
}

__global__ __launch_bounds__(1024) void k_scan2(int* a, int na, int* b, int nb) {
    int* p = (blockIdx.x == 0) ? a : b;
    int n  = (blockIdx.x == 0) ? na : nb;
    __shared__ int sums[1024];
    int t = threadIdx.x;
    int C = (n + 1023) >> 10;
    int base = t * C;
    int s = 0;
    for (int j = 0; j < C; ++j) { int i = base + j; if (i < n) s += p[i]; }
    sums[t] = s;
    __syncthreads();
    for (int off = 1; off < 1024; off <<= 1) {
        int v = (t >= off) ? sums[t - off] : 0;
        __syncthreads();
        sums[t] += v;
        __syncthreads();
    }
    int run = (t == 0) ? 0 : sums[t - 1];
    for (int j = 0; j < C; ++j) {
        int i = base + j;
        if (i < n) { int v = p[i]; p[i] = run; run += v; }
    }
}

__global__ void k_scatter(const int* __restrict__ src_s, const int* __restrict__ dst_s, int Es,
                          const int* __restrict__ src_n, const int* __restrict__ dst_n, int En,
                          int* __restrict__ cur_s, int* __restrict__ cur_n,
                          int* __restrict__ csr_s, int* __restrict__ csr_n) {
    int i = blockIdx.x * 256 + threadIdx.x;
    if (i < Es) {
        int pos = atomicAdd(&cur_s[dst_s[i]], 1);
        csr_s[pos] = src_s[i];
    }
    int j = i - Es;
    if (j >= 0 && j < En) {
        int pos = atomicAdd(&cur_n[dst_n[j]], 1);
        csr_n[pos] = src_n[j];
    }
}

// ---------------------------------------------------------------------------
// GATv2, both layers fused by contiguous block ranges (block < gNs -> seen).
// R14: the per-edge fs recompute (16 pkfma + 8 readlane, plus a scalar branch
// per edge) is replaced by a GATHER of precomputed bf16 fs rows. The edge
// loop is now branch-free straight-line code: chunks of 8 edges, indices
// clamped to deg-1 (padded slots reload the last row -> cache hit, ~zero
// extra traffic) and their softmax weight zeroed by cndmask. Indices are
// prefetched 2 chunks ahead, fs rows 1 chunk ahead -> latency hidden under
// the previous chunk's compute; no per-edge s_cbranch, so the scheduler can
// interleave the 8 independent edges and hide the DPP-rowsum / v_exp chains.
// ---------------------------------------------------------------------------
__global__ __launch_bounds__(256) void k_gat(
    const unsigned short* __restrict__ fsrc_s, const int* __restrict__ pfx_s, const int* __restrict__ csr_s,
    const float* __restrict__ Wd_s, const float* __restrict__ bd_s,
    const float* __restrict__ at_s,
    const float* __restrict__ Wr_s, const float* __restrict__ br_s,
    const unsigned short* __restrict__ fsrc_n, const int* __restrict__ pfx_n, const int* __restrict__ csr_n,
    const float* __restrict__ Wd_n, const float* __restrict__ bd_n,
    const float* __restrict__ at_n,
    const float* __restrict__ Wr_n, const float* __restrict__ br_n,
    const float* __restrict__ x_ag,
    unsigned short* __restrict__ xcat, int n_dst, int gNs)
{
    const bool seen = (int)blockIdx.x < gNs;
    const unsigned short* fsrc = seen ? fsrc_s : fsrc_n;
    const int*   pfx   = seen ? pfx_s  : pfx_n;
    const int*   csr   = seen ? csr_s  : csr_n;
    const float* Wd    = seen ? Wd_s   : Wd_n;
    const float* bd    = seen ? bd_s   : bd_n;
    const float* at    = seen ? at_s   : at_n;
    const float* Wr    = seen ? Wr_s   : Wr_n;
    const float* br    = seen ? br_s   : br_n;
    const int col = seen ? 0 : 256;
    const int blk = seen ? (int)blockIdx.x : (int)blockIdx.x - gNs;

    const int t = threadIdx.x;
    const int wave = t >> 6, lane = t & 63;
    const int d0 = lane * 4;

    // ---- gather the wave's 4 agent rows: lane L = feat (L&15) of node L>>4
    int gnode = blk * 16 + ((lane >> 4) << 2) + wave;
    int gn = (gnode < n_dst) ? gnode : (n_dst - 1);
    float xag = x_ag[(size_t)gn * 16 + (lane & 15)];

    // ---- prefetch the 4 nodes' edge ranges (overlaps fd/fr pass)
    int e_start[4], e_end[4];
#pragma unroll
    for (int j = 0; j < 4; ++j) {
        int nd = blk * 16 + j * 4 + wave;
        nd = (nd < n_dst) ? nd : (n_dst - 1);
        e_end[j]   = pfx[nd];
        e_start[j] = nd ? pfx[nd - 1] : 0;
    }

    // ---- fd/fr for all 4 nodes in ONE pass over the 32 weight rows (packed)
    f32x2 fd01[4], fd23[4], fr01[4], fr23[4];
    {
        float4 bdv = *(const float4*)&bd[d0];
        float4 brv = *(const float4*)&br[d0];
#pragma unroll
        for (int j = 0; j < 4; ++j) {
            fd01[j] = (f32x2){bdv.x, bdv.y}; fd23[j] = (f32x2){bdv.z, bdv.w};
            fr01[j] = (f32x2){brv.x, brv.y}; fr23[j] = (f32x2){brv.z, brv.w};
        }
#pragma unroll
        for (int k = 0; k < 16; ++k) {
            float4 wd = *(const float4*)&Wd[k * 256 + d0];
            float4 wr = *(const float4*)&Wr[k * 256 + d0];
            f32x2 wd01 = {wd.x, wd.y}, wd23 = {wd.z, wd.w};
            f32x2 wr01 = {wr.x, wr.y}, wr23 = {wr.z, wr.w};
#pragma unroll
            for (int j = 0; j < 4; ++j) {
                f32x2 xk = splat2(rlane(xag, j * 16 + k));
                fd01[j] = pkfma(xk, wd01, fd01[j]);
                fd23[j] = pkfma(xk, wd23, fd23[j]);
                fr01[j] = pkfma(xk, wr01, fr01[j]);
                fr23[j] = pkfma(xk, wr23, fr23[j]);
            }
        }
    }

    f32x2 at01, at23;
    {
        float4 a4 = *(const float4*)&at[d0];
        at01 = (f32x2){a4.x, a4.y}; at23 = (f32x2){a4.z, a4.w};
    }

#pragma unroll
    for (int rep = 0; rep < 4; ++rep) {
        const int node = blk * 16 + rep * 4 + wave;
        if (node >= n_dst) continue;

        const int start = e_start[rep];
        const int deg   = e_end[rep] - start;
        const f32x2 fd01r = fd01[rep], fd23r = fd23[rep];

        float l = 0.f;
        f32x2 a01 = {0.f, 0.f}, a23 = {0.f, 0.f};

        if (deg > 0) {
            // clamped edge index: padded slots alias row deg-1 (cached)
            int iN[8];          // indices of NEXT chunk (wave-uniform)
            uint2 fC[8];        // fs rows of CURRENT chunk (4 bf16/lane each)
#pragma unroll
            for (int j = 0; j < 8; ++j) {
                int e = (j < deg) ? j : deg - 1;
                iN[j] = csr[start + e];
            }
#pragma unroll
            for (int j = 0; j < 8; ++j)
                fC[j] = *(const uint2*)&fsrc[(((unsigned)iN[j]) << 8) | (unsigned)d0];
#pragma unroll
            for (int j = 0; j < 8; ++j) {
                int e = 8 + j; e = (e < deg) ? e : deg - 1;
                iN[j] = csr[start + e];
            }

            for (int base = 0; base < deg; base += 8) {
                uint2 fN[8]; int iN2[8];
                // issue next chunk's fs loads (indices arrived last chunk)
#pragma unroll
                for (int j = 0; j < 8; ++j)
                    fN[j] = *(const uint2*)&fsrc[(((unsigned)iN[j]) << 8) | (unsigned)d0];
                // issue indices two chunks ahead
#pragma unroll
                for (int j = 0; j < 8; ++j) {
                    int e = base + 16 + j; e = (e < deg) ? e : deg - 1;
                    iN2[j] = csr[start + e];
                }
                // compute current chunk: 8 independent edges, no branches
#pragma unroll
                for (int j = 0; j < 8; ++j) {
                    unsigned lo = fC[j].x, hi = fC[j].y;
                    f32x2 fs01, fs23;
                    fs01.x = __uint_as_float(lo << 16);
                    fs01.y = __uint_as_float(lo & 0xffff0000u);
                    fs23.x = __uint_as_float(hi << 16);
                    fs23.y = __uint_as_float(hi & 0xffff0000u);

                    f32x2 t01 = fs01 + fd01r;
                    f32x2 t23 = fs23 + fd23r;
                    t01 = __builtin_elementwise_max(t01, NEG * t01);
                    t23 = __builtin_elementwise_max(t23, NEG * t23);

                    f32x2 scp = t01 * at01;
                    scp = pkfma(t23, at23, scp);
                    float sc = scp.x + scp.y;
                    sc = rowsum16(sc);

                    float p = __expf(sc);          // no max shift: |sc| bounded
                    p = (base + j < deg) ? p : 0.f;  // padded slot -> weight 0
                    l += p;
                    f32x2 pp = splat2(p);
                    a01 = pkfma(pp, fs01, a01);
                    a23 = pkfma(pp, fs23, a23);
                }
                // rotate double buffers
#pragma unroll
                for (int j = 0; j < 8; ++j) { fC[j] = fN[j]; iN[j] = iN2[j]; }
            }
        }

        float inv = (l > 0.f) ? 1.f / l : 0.f;   // zero in-degree -> rst = 0
        ushort4 o;
        o.x = f2bf(fmaxf(fmaf(a01.x, inv, fr01[rep].x), 0.f));
        o.y = f2bf(fmaxf(fmaf(a01.y, inv, fr01[rep].y), 0.f));
        o.z = f2bf(fmaxf(fmaf(a23.x, inv, fr23[rep].x), 0.f));
        o.w = f2bf(fmaxf(fmaf(a23.y, inv, fr23[rep].y), 0.f));
        *(ushort4*)&xcat[(size_t)node * 512 + col + d0] = o;
    }
}

// ---------------------------------------------------------------------------
// out = relu(X[M,512]bf16 @ W[512,256]bf16 + b) via mfma_f32_16x16x32_bf16.
// Block = 4 waves: rows rbase..rbase+15, wave w covers cols 64w..64w+63.
// A/B frags straight from L2 (no LDS). D: col n=lane&15, row m=q*4+reg.
// ---------------------------------------------------------------------------
__global__ __launch_bounds__(256) void k_mlp(
    const unsigned short* __restrict__ X, const unsigned short* __restrict__ Wt,
    const float* __restrict__ b, float* __restrict__ out, int M)
{
    const int t = threadIdx.x;
    const int wave = t >> 6, lane = t & 63;
    const int m16 = lane & 15, q = lane >> 4;
    const int rbase = blockIdx.x * 16;
    const int nbase = wave * 64;

    int rowa = rbase + m16; if (rowa >= M) rowa = M - 1;
    const unsigned short* xp = X + (size_t)rowa * 512 + q * 8;
    const unsigned short* w0 = Wt + (size_t)(nbase + m16) * 512 + q * 8;
    const unsigned short* w1 = w0 + 16 * 512;
    const unsigned short* w2 = w0 + 32 * 512;
    const unsigned short* w3 = w0 + 48 * 512;

    f32x4 ac0 = {0.f, 0.f, 0.f, 0.f}, ac1 = ac0, ac2 = ac0, ac3 = ac0;

#pragma unroll
    for (int k0 = 0; k0 < 512; k0 += 32) {
        bf16x8 a  = *(const bf16x8*)(xp + k0);
        bf16x8 b0 = *(const bf16x8*)(w0 + k0);
        bf16x8 b1 = *(const bf16x8*)(w1 + k0);
        bf16x8 b2 = *(const bf16x8*)(w2 + k0);
        bf16x8 b3 = *(const bf16x8*)(w3 + k0);
        ac0 = __builtin_amdgcn_mfma_f32_16x16x32_bf16(a, b0, ac0, 0, 0, 0);
        ac1 = __builtin_amdgcn_mfma_f32_16x16x32_bf16(a, b1, ac1, 0, 0, 0);
        ac2 = __builtin_amdgcn_mfma_f32_16x16x32_bf16(a, b2, ac2, 0, 0, 0);
        ac3 = __builtin_amdgcn_mfma_f32_16x16x32_bf16(a, b3, ac3, 0, 0, 0);
    }

#define EPI(AC, J) { \
        int coln = nbase + (J) * 16 + m16; \
        float bias = b[coln]; \
        _Pragma("unroll") \
        for (int r = 0; r < 4; ++r) { \
            int orow = rbase + q * 4 + r; \
            if (orow < M) \
                out[(size_t)orow * 256 + coln] = fmaxf(AC[r] + bias, 0.f); \
        } }
    EPI(ac0, 0) EPI(ac1, 1) EPI(ac2, 2) EPI(ac3, 3)
#undef EPI
}

// ---------------------------------------------------------------------------
extern "C" void kernel_launch(void* const* d_in, const int* in_sizes, int n_in,
                              void* d_out, int out_size, void* d_ws, size_t ws_size,
                              hipStream_t stream) {
    const float* x_gt   = (const float*)d_in[0];
    const float* x_ubs  = (const float*)d_in[1];
    const float* x_ag   = (const float*)d_in[2];
    const int* seen_src = (const int*)d_in[3];
    const int* seen_dst = (const int*)d_in[4];
    const int* near_src = (const int*)d_in[5];
    const int* near_dst = (const int*)d_in[6];
    const float* Ws_s = (const float*)d_in[7];  const float* bs_s = (const float*)d_in[8];
    const float* Wd_s = (const float*)d_in[9];  const float* bd_s = (const float*)d_in[10];
    const float* at_s = (const float*)d_in[11];
    const float* Wr_s = (const float*)d_in[12]; const float* br_s = (const float*)d_in[13];
    const float* Ws_n = (const float*)d_in[14]; const float* bs_n = (const float*)d_in[15];
    const float* Wd_n = (const float*)d_in[16]; const float* bd_n = (const float*)d_in[17];
    const float* at_n = (const float*)d_in[18];
    const float* Wr_n = (const float*)d_in[19]; const float* br_n = (const float*)d_in[20];
    const float* W_a  = (const float*)d_in[21]; const float* b_a  = (const float*)d_in[22];

    const int n_ag = in_sizes[2] / 16;
    const int E_s  = in_sizes[3];
    const int E_n  = in_sizes[5];
    const int Ns   = in_sizes[0] / 8;    // gt source nodes   (F_GT = 8)
    const int Nn   = in_sizes[1] / 8;    // ubs source nodes  (F_UBS = 8)

    char* ws = (char*)d_ws;
    int* cur_s = (int*)ws;              ws += (size_t)n_ag * 4;
    int* cur_n = (int*)ws;              ws += (size_t)n_ag * 4;
    int* csr_s = (int*)ws;              ws += (size_t)E_s * 4;
    int* csr_n = (int*)ws;              ws += (size_t)E_n * 4;
    unsigned short* xcat = (unsigned short*)ws;  ws += (size_t)n_ag * 512 * 2;
    unsigned short* Wt   = (unsigned short*)ws;  ws += (size_t)512 * 256 * 2;
    unsigned short* fs_s = (unsigned short*)ws;  ws += (size_t)Ns * 256 * 2;  // 51.2 MB
    unsigned short* fs_n = (unsigned short*)ws;  // 10.2 MB

    hipMemsetAsync(cur_s, 0, (size_t)n_ag * 8, stream);  // cur_s, cur_n contiguous

    int gE = (E_s + E_n + 255) / 256;
    int gH = (Ns + Nn + 3) / 4;          // 4 fs-nodes (waves) per block
    if (gH < gE) gH = gE;
    k_hist_wt_fs<<<gH, 256, 0, stream>>>(seen_dst, E_s, near_dst, E_n, cur_s, cur_n,
                                         W_a, Wt,
                                         x_gt,  Ws_s, bs_s, fs_s, Ns,
                                         x_ubs, Ws_n, bs_n, fs_n, Nn);
    k_scan2<<<2, 1024, 0, stream>>>(cur_s, n_ag, cur_n, n_ag);
    k_scatter<<<gE, 256, 0, stream>>>(seen_src, seen_dst, E_s, near_src, near_dst, E_n,
                                      cur_s, cur_n, csr_s, csr_n);

    int gN = (n_ag + 15) / 16;   // 16 nodes per block (4 waves x 4 nodes)
    k_gat<<<2 * gN, 256, 0, stream>>>(
        fs_s, cur_s, csr_s, Wd_s, bd_s, at_s, Wr_s, br_s,
        fs_n, cur_n, csr_n, Wd_n, bd_n, at_n, Wr_n, br_n,
        x_ag, xcat, n_ag, gN);

    k_mlp<<<(n_ag + 15) / 16, 256, 0, stream>>>(xcat, Wt, b_a, (float*)d_out, n_ag);
}

// Round 2
// 335.716 us; speedup vs baseline: 1.0124x; 1.0124x over previous
//
#include <hip/hip_runtime.h>
#include <math.h>

#define NEG 0.2f

typedef short bf16x8 __attribute__((ext_vector_type(8)));
typedef float f32x4  __attribute__((ext_vector_type(4)));
typedef float f32x2  __attribute__((ext_vector_type(2)));

// ---------------------------------------------------------------------------
// helpers
// ---------------------------------------------------------------------------
static __device__ __forceinline__ f32x2 pkfma(f32x2 a, f32x2 b, f32x2 c) {
    return __builtin_elementwise_fma(a, b, c);   // -> v_pk_fma_f32
}
static __device__ __forceinline__ f32x2 splat2(float x) { return (f32x2){x, x}; }

static __device__ __forceinline__ unsigned short f2bf(float f) {   // RNE, finite
    unsigned int x = __float_as_uint(f);
    unsigned int r = (x + 0x7FFFu + ((x >> 16) & 1u)) >> 16;
    return (unsigned short)r;
}
static __device__ __forceinline__ float rlane(float v, int l) {
    return __int_as_float(__builtin_amdgcn_readlane(__float_as_int(v), l));
}

// Sum across each 16-lane DPP row (head h = lanes 16h..16h+15).
#define DPP_ADD(x, ctrl) \
    ((x) + __int_as_float(__builtin_amdgcn_update_dpp( \
        __float_as_int(x), __float_as_int(x), (ctrl), 0xF, 0xF, true)))
static __device__ __forceinline__ float rowsum16(float v) {
    v = DPP_ADD(v, 0xB1);   // quad_perm xor1
    v = DPP_ADD(v, 0x4E);   // quad_perm xor2
    v = DPP_ADD(v, 0x141);  // row_half_mirror
    v = DPP_ADD(v, 0x140);  // row_mirror
    return v;
}

// ---------------------------------------------------------------------------
// CSR build (separate dispatches; cooperative grid.sync was ~120us/sync, R7)
// ---------------------------------------------------------------------------
__global__ void k_hist_wt(const int* __restrict__ dst_s, int Es,
                          const int* __restrict__ dst_n, int En,
                          int* __restrict__ deg_s, int* __restrict__ deg_n,
                          const float* __restrict__ W, unsigned short* __restrict__ Wt) {
    int i = blockIdx.x * 256 + threadIdx.x;
    if (i < Es) atomicAdd(&deg_s[dst_s[i]], 1);
    int j = i - Es;
    if (j >= 0 && j < En) atomicAdd(&deg_n[dst_n[j]], 1);
    if (i < 512 * 256) {                 // W[512][256] f32 -> Wt[256][512] bf16
        int k = i >> 8, n = i & 255;
        Wt[(size_t)n * 512 + k] = f2bf(W[i]);
    }
}

__global__ __launch_bounds__(1024) void k_scan2(int* a, int na, int* b, int nb) {
    int* p = (blockIdx.x == 0) ? a : b;
    int n  = (blockIdx.x == 0) ? na : nb;
    __shared__ int sums[1024];
    int t = threadIdx.x;
    int C = (n + 1023) >> 10;
    int base = t * C;
    int s = 0;
    for (int j = 0; j < C; ++j) { int i = base + j; if (i < n) s += p[i]; }
    sums[t] = s;
    __syncthreads();
    for (int off = 1; off < 1024; off <<= 1) {
        int v = (t >= off) ? sums[t - off] : 0;
        __syncthreads();
        sums[t] += v;
        __syncthreads();
    }
    int run = (t == 0) ? 0 : sums[t - 1];
    for (int j = 0; j < C; ++j) {
        int i = base + j;
        if (i < n) { int v = p[i]; p[i] = run; run += v; }
    }
}

__global__ void k_scatter(const int* __restrict__ src_s, const int* __restrict__ dst_s, int Es,
                          const int* __restrict__ src_n, const int* __restrict__ dst_n, int En,
                          int* __restrict__ cur_s, int* __restrict__ cur_n,
                          int* __restrict__ csr_s, int* __restrict__ csr_n) {
    int i = blockIdx.x * 256 + threadIdx.x;
    if (i < Es) {
        int pos = atomicAdd(&cur_s[dst_s[i]], 1);
        csr_s[pos] = src_s[i];
    }
    int j = i - Es;
    if (j >= 0 && j < En) {
        int pos = atomicAdd(&cur_n[dst_n[j]], 1);
        csr_n[pos] = src_n[j];
    }
}

// ---------------------------------------------------------------------------
// GATv2, both layers fused by contiguous block ranges (block < gNs -> seen).
// R15: post-mortem of R14 showed k_gat is LATENCY-bound (per-SIMD issue
// ~15%), and the stall is the 4x per-rep pipeline restart: with mean degree
// 16/8 each rep is {cold csr load -> wait -> cold x load -> wait -> 1-2
// chunks -> drain}. This version flattens the 4 reps into ONE chunk stream
// with a steady 3-stage pipeline that crosses rep boundaries:
//   stage A: csr indices of chunk n+2 in flight
//   stage B: x rows    of chunk n+1 in flight
//   stage C: compute chunk n (8 edges, branch-free, fs recomputed in-reg)
// Only one pipeline fill per wave, hidden under the fd/fr prologue.
// fs gather (R14) reverted: +34us of precompute/HBM cost bought only 6%.
// Chunk scheduling is wave-uniform scalar math; per-rep accumulators are
// statically indexed (chunk partials merged via uniform 4-way branch).
// ---------------------------------------------------------------------------
__global__ __launch_bounds__(256) void k_gat(
    const float* __restrict__ xsrc_s, const int* __restrict__ pfx_s, const int* __restrict__ csr_s,
    const float* __restrict__ Ws_s, const float* __restrict__ bs_s,
    const float* __restrict__ Wd_s, const float* __restrict__ bd_s,
    const float* __restrict__ at_s,
    const float* __restrict__ Wr_s, const float* __restrict__ br_s,
    const float* __restrict__ xsrc_n, const int* __restrict__ pfx_n, const int* __restrict__ csr_n,
    const float* __restrict__ Ws_n, const float* __restrict__ bs_n,
    const float* __restrict__ Wd_n, const float* __restrict__ bd_n,
    const float* __restrict__ at_n,
    const float* __restrict__ Wr_n, const float* __restrict__ br_n,
    const float* __restrict__ x_ag,
    unsigned short* __restrict__ xcat, int n_dst, int gNs)
{
    const bool seen = (int)blockIdx.x < gNs;
    const float* x_src = seen ? xsrc_s : xsrc_n;
    const int*   pfx   = seen ? pfx_s  : pfx_n;
    const int*   csr   = seen ? csr_s  : csr_n;
    const float* Ws    = seen ? Ws_s   : Ws_n;
    const float* bs    = seen ? bs_s   : bs_n;
    const float* Wd    = seen ? Wd_s   : Wd_n;
    const float* bd    = seen ? bd_s   : bd_n;
    const float* at    = seen ? at_s   : at_n;
    const float* Wr    = seen ? Wr_s   : Wr_n;
    const float* br    = seen ? br_s   : br_n;
    const int col = seen ? 0 : 256;
    const int blk = seen ? (int)blockIdx.x : (int)blockIdx.x - gNs;

    const int t = threadIdx.x;
    const int wave = t >> 6, lane = t & 63;
    const int d0 = lane * 4;
    const int gs = lane >> 3;   // edge slot 0..7 within chunk
    const int w8 = lane & 7;    // word within the 8-float src row

    // ---- gather the wave's 4 agent rows: lane L = feat (L&15) of node L>>4
    int gnode = blk * 16 + ((lane >> 4) << 2) + wave;
    int gn = (gnode < n_dst) ? gnode : (n_dst - 1);
    float xag = x_ag[(size_t)gn * 16 + (lane & 15)];

    // ---- the 4 nodes' edge ranges (issued first; overlaps everything below)
    int st0, st1, st2, st3, dg0, dg1, dg2, dg3;
    {
        int nd0 = blk * 16 + 0 * 4 + wave; nd0 = (nd0 < n_dst) ? nd0 : n_dst - 1;
        int nd1 = blk * 16 + 1 * 4 + wave; nd1 = (nd1 < n_dst) ? nd1 : n_dst - 1;
        int nd2 = blk * 16 + 2 * 4 + wave; nd2 = (nd2 < n_dst) ? nd2 : n_dst - 1;
        int nd3 = blk * 16 + 3 * 4 + wave; nd3 = (nd3 < n_dst) ? nd3 : n_dst - 1;
        int e0 = pfx[nd0], e1 = pfx[nd1], e2 = pfx[nd2], e3 = pfx[nd3];
        st0 = nd0 ? pfx[nd0 - 1] : 0;
        st1 = nd1 ? pfx[nd1 - 1] : 0;
        st2 = nd2 ? pfx[nd2 - 1] : 0;
        st3 = nd3 ? pfx[nd3 - 1] : 0;
        dg0 = e0 - st0; dg1 = e1 - st1; dg2 = e2 - st2; dg3 = e3 - st3;
    }

#define DEG(r)  ((r) == 0 ? dg0 : ((r) == 1 ? dg1 : ((r) == 2 ? dg2 : dg3)))
#define STRT(r) ((r) == 0 ? st0 : ((r) == 1 ? st1 : ((r) == 2 ? st2 : st3)))
    // advance (r,b) to the next chunk, skipping empty reps (call only if r<4)
#define ADV(r, b) { b += 8; if (b >= DEG(r)) { b = 0; ++r; \
        if (r < 4 && DEG(r) == 0) ++r; \
        if (r < 4 && DEG(r) == 0) ++r; \
        if (r < 4 && DEG(r) == 0) ++r; } }

    // ---- first chunk coords + issue its csr-index load (latency hidden by
    //      the fd/fr pass below)
    int ra = 0, ba = 0;
    if (DEG(ra) == 0) ++ra;
    if (ra < 4 && DEG(ra) == 0) ++ra;
    if (ra < 4 && DEG(ra) == 0) ++ra;
    if (ra < 4 && DEG(ra) == 0) ++ra;
    int ia = 0;
    if (ra < 4) {
        int dg = DEG(ra);
        int e = ba + gs; e = (e < dg) ? e : dg - 1;
        ia = csr[STRT(ra) + e];
    }

    // ---- fd/fr for all 4 nodes in ONE pass over the 32 weight rows (packed)
    f32x2 fd01[4], fd23[4], fr01[4], fr23[4];
    {
        float4 bdv = *(const float4*)&bd[d0];
        float4 brv = *(const float4*)&br[d0];
#pragma unroll
        for (int j = 0; j < 4; ++j) {
            fd01[j] = (f32x2){bdv.x, bdv.y}; fd23[j] = (f32x2){bdv.z, bdv.w};
            fr01[j] = (f32x2){brv.x, brv.y}; fr23[j] = (f32x2){brv.z, brv.w};
        }
#pragma unroll
        for (int k = 0; k < 16; ++k) {
            float4 wd = *(const float4*)&Wd[k * 256 + d0];
            float4 wr = *(const float4*)&Wr[k * 256 + d0];
            f32x2 wd01 = {wd.x, wd.y}, wd23 = {wd.z, wd.w};
            f32x2 wr01 = {wr.x, wr.y}, wr23 = {wr.z, wr.w};
#pragma unroll
            for (int j = 0; j < 4; ++j) {
                f32x2 xk = splat2(rlane(xag, j * 16 + k));
                fd01[j] = pkfma(xk, wd01, fd01[j]);
                fd23[j] = pkfma(xk, wd23, fd23[j]);
                fr01[j] = pkfma(xk, wr01, fr01[j]);
                fr23[j] = pkfma(xk, wr23, fr23[j]);
            }
        }
    }

    // ---- fill pipeline: x rows of chunk0, csr indices of chunk1
    int rb = ra, bb = ba;
    if (rb < 4) ADV(rb, bb);
    float xa = 0.f;
    if (ra < 4) xa = x_src[(size_t)ia * 8 + w8];
    int ib = 0;
    if (rb < 4) {
        int dg = DEG(rb);
        int e = bb + gs; e = (e < dg) ? e : dg - 1;
        ib = csr[STRT(rb) + e];
    }

    // ---- wave-lifetime edge-loop constants (packed pairs)
    f32x2 ws01[8], ws23[8];
#pragma unroll
    for (int k = 0; k < 8; ++k) {
        float4 w = *(const float4*)&Ws[k * 256 + d0];
        ws01[k] = (f32x2){w.x, w.y};
        ws23[k] = (f32x2){w.z, w.w};
    }
    f32x2 bs01, bs23, at01, at23;
    {
        float4 b4 = *(const float4*)&bs[d0];
        float4 a4 = *(const float4*)&at[d0];
        bs01 = (f32x2){b4.x, b4.y}; bs23 = (f32x2){b4.z, b4.w};
        at01 = (f32x2){a4.x, a4.y}; at23 = (f32x2){a4.z, a4.w};
    }

    // ---- per-rep accumulators (statically indexed)
    float L0 = 0.f, L1 = 0.f, L2 = 0.f, L3 = 0.f;
    f32x2 A010 = {0.f, 0.f}, A230 = {0.f, 0.f};
    f32x2 A011 = {0.f, 0.f}, A231 = {0.f, 0.f};
    f32x2 A012 = {0.f, 0.f}, A232 = {0.f, 0.f};
    f32x2 A013 = {0.f, 0.f}, A233 = {0.f, 0.f};

    // ---- flat chunk stream: compute chunk n, x of n+1 and idx of n+2 in flight
    while (ra < 4) {
        int rc = rb, bc = bb;
        if (rc < 4) ADV(rc, bc);
        float xb = 0.f;
        if (rb < 4) xb = x_src[(size_t)ib * 8 + w8];
        int ic = 0;
        if (rc < 4) {
            int dg = DEG(rc);
            int e = bc + gs; e = (e < dg) ? e : dg - 1;
            ic = csr[STRT(rc) + e];
        }

        const int dga = DEG(ra);
        const f32x2 fd01c = (ra == 0) ? fd01[0] : ((ra == 1) ? fd01[1] : ((ra == 2) ? fd01[2] : fd01[3]));
        const f32x2 fd23c = (ra == 0) ? fd23[0] : ((ra == 1) ? fd23[1] : ((ra == 2) ? fd23[2] : fd23[3]));

        float cll = 0.f;
        f32x2 cl01 = {0.f, 0.f}, cl23 = {0.f, 0.f};
#pragma unroll
        for (int j = 0; j < 8; ++j) {
            f32x2 x0 = splat2(rlane(xa, j * 8 + 0));
            f32x2 x1 = splat2(rlane(xa, j * 8 + 1));
            f32x2 x2 = splat2(rlane(xa, j * 8 + 2));
            f32x2 x3 = splat2(rlane(xa, j * 8 + 3));
            f32x2 x4 = splat2(rlane(xa, j * 8 + 4));
            f32x2 x5 = splat2(rlane(xa, j * 8 + 5));
            f32x2 x6 = splat2(rlane(xa, j * 8 + 6));
            f32x2 x7 = splat2(rlane(xa, j * 8 + 7));

            f32x2 fs01 = bs01, fs23 = bs23;
            fs01 = pkfma(x0, ws01[0], fs01); fs23 = pkfma(x0, ws23[0], fs23);
            fs01 = pkfma(x1, ws01[1], fs01); fs23 = pkfma(x1, ws23[1], fs23);
            fs01 = pkfma(x2, ws01[2], fs01); fs23 = pkfma(x2, ws23[2], fs23);
            fs01 = pkfma(x3, ws01[3], fs01); fs23 = pkfma(x3, ws23[3], fs23);
            fs01 = pkfma(x4, ws01[4], fs01); fs23 = pkfma(x4, ws23[4], fs23);
            fs01 = pkfma(x5, ws01[5], fs01); fs23 = pkfma(x5, ws23[5], fs23);
            fs01 = pkfma(x6, ws01[6], fs01); fs23 = pkfma(x6, ws23[6], fs23);
            fs01 = pkfma(x7, ws01[7], fs01); fs23 = pkfma(x7, ws23[7], fs23);

            // leaky relu of (fs+fd): max(v, 0.2v), packed
            f32x2 t01 = fs01 + fd01c;
            f32x2 t23 = fs23 + fd23c;
            t01 = __builtin_elementwise_max(t01, NEG * t01);
            t23 = __builtin_elementwise_max(t23, NEG * t23);

            f32x2 scp = t01 * at01;
            scp = pkfma(t23, at23, scp);
            float sc = scp.x + scp.y;
            sc = rowsum16(sc);

            float p = __expf(sc);           // no max shift: |sc| bounded
            p = (ba + j < dga) ? p : 0.f;   // padded slot -> weight 0
            cll += p;
            f32x2 pp = splat2(p);
            cl01 = pkfma(pp, fs01, cl01);
            cl23 = pkfma(pp, fs23, cl23);
        }

        // merge chunk partials into the owning rep (uniform branch)
        if (ra == 0)      { L0 += cll; A010 += cl01; A230 += cl23; }
        else if (ra == 1) { L1 += cll; A011 += cl01; A231 += cl23; }
        else if (ra == 2) { L2 += cll; A012 += cl01; A232 += cl23; }
        else              { L3 += cll; A013 += cl01; A233 += cl23; }

        // rotate pipeline
        ra = rb; ba = bb; xa = xb;
        rb = rc; bb = bc; ib = ic;
    }

#undef ADV
#undef STRT
#undef DEG

    // ---- epilogue: softmax-normalize, add residual, relu, store bf16
#define OUTR(R, LR, A01R, A23R) { \
        int node = blk * 16 + (R) * 4 + wave; \
        if (node < n_dst) { \
            float inv = ((LR) > 0.f) ? 1.f / (LR) : 0.f; \
            ushort4 o; \
            o.x = f2bf(fmaxf(fmaf(A01R.x, inv, fr01[R].x), 0.f)); \
            o.y = f2bf(fmaxf(fmaf(A01R.y, inv, fr01[R].y), 0.f)); \
            o.z = f2bf(fmaxf(fmaf(A23R.x, inv, fr23[R].x), 0.f)); \
            o.w = f2bf(fmaxf(fmaf(A23R.y, inv, fr23[R].y), 0.f)); \
            *(ushort4*)&xcat[(size_t)node * 512 + col + d0] = o; \
        } }
    OUTR(0, L0, A010, A230)
    OUTR(1, L1, A011, A231)
    OUTR(2, L2, A012, A232)
    OUTR(3, L3, A013, A233)
#undef OUTR
}

// ---------------------------------------------------------------------------
// out = relu(X[M,512]bf16 @ W[512,256]bf16 + b) via mfma_f32_16x16x32_bf16.
// Block = 4 waves: rows rbase..rbase+15, wave w covers cols 64w..64w+63.
// A/B frags straight from L2 (no LDS). D: col n=lane&15, row m=q*4+reg.
// ---------------------------------------------------------------------------
__global__ __launch_bounds__(256) void k_mlp(
    const unsigned short* __restrict__ X, const unsigned short* __restrict__ Wt,
    const float* __restrict__ b, float* __restrict__ out, int M)
{
    const int t = threadIdx.x;
    const int wave = t >> 6, lane = t & 63;
    const int m16 = lane & 15, q = lane >> 4;
    const int rbase = blockIdx.x * 16;
    const int nbase = wave * 64;

    int rowa = rbase + m16; if (rowa >= M) rowa = M - 1;
    const unsigned short* xp = X + (size_t)rowa * 512 + q * 8;
    const unsigned short* w0 = Wt + (size_t)(nbase + m16) * 512 + q * 8;
    const unsigned short* w1 = w0 + 16 * 512;
    const unsigned short* w2 = w0 + 32 * 512;
    const unsigned short* w3 = w0 + 48 * 512;

    f32x4 ac0 = {0.f, 0.f, 0.f, 0.f}, ac1 = ac0, ac2 = ac0, ac3 = ac0;

#pragma unroll
    for (int k0 = 0; k0 < 512; k0 += 32) {
        bf16x8 a  = *(const bf16x8*)(xp + k0);
        bf16x8 b0 = *(const bf16x8*)(w0 + k0);
        bf16x8 b1 = *(const bf16x8*)(w1 + k0);
        bf16x8 b2 = *(const bf16x8*)(w2 + k0);
        bf16x8 b3 = *(const bf16x8*)(w3 + k0);
        ac0 = __builtin_amdgcn_mfma_f32_16x16x32_bf16(a, b0, ac0, 0, 0, 0);
        ac1 = __builtin_amdgcn_mfma_f32_16x16x32_bf16(a, b1, ac1, 0, 0, 0);
        ac2 = __builtin_amdgcn_mfma_f32_16x16x32_bf16(a, b2, ac2, 0, 0, 0);
        ac3 = __builtin_amdgcn_mfma_f32_16x16x32_bf16(a, b3, ac3, 0, 0, 0);
    }

#define EPI(AC, J) { \
        int coln = nbase + (J) * 16 + m16; \
        float bias = b[coln]; \
        _Pragma("unroll") \
        for (int r = 0; r < 4; ++r) { \
            int orow = rbase + q * 4 + r; \
            if (orow < M) \
                out[(size_t)orow * 256 + coln] = fmaxf(AC[r] + bias, 0.f); \
        } }
    EPI(ac0, 0) EPI(ac1, 1) EPI(ac2, 2) EPI(ac3, 3)
#undef EPI
}

// ---------------------------------------------------------------------------
extern "C" void kernel_launch(void* const* d_in, const int* in_sizes, int n_in,
                              void* d_out, int out_size, void* d_ws, size_t ws_size,
                              hipStream_t stream) {
    const float* x_gt   = (const float*)d_in[0];
    const float* x_ubs  = (const float*)d_in[1];
    const float* x_ag   = (const float*)d_in[2];
    const int* seen_src = (const int*)d_in[3];
    const int* seen_dst = (const int*)d_in[4];
    const int* near_src = (const int*)d_in[5];
    const int* near_dst = (const int*)d_in[6];
    const float* Ws_s = (const float*)d_in[7];  const float* bs_s = (const float*)d_in[8];
    const float* Wd_s = (const float*)d_in[9];  const float* bd_s = (const float*)d_in[10];
    const float* at_s = (const float*)d_in[11];
    const float* Wr_s = (const float*)d_in[12]; const float* br_s = (const float*)d_in[13];
    const float* Ws_n = (const float*)d_in[14]; const float* bs_n = (const float*)d_in[15];
    const float* Wd_n = (const float*)d_in[16]; const float* bd_n = (const float*)d_in[17];
    const float* at_n = (const float*)d_in[18];
    const float* Wr_n = (const float*)d_in[19]; const float* br_n = (const float*)d_in[20];
    const float* W_a  = (const float*)d_in[21]; const float* b_a  = (const float*)d_in[22];

    const int n_ag = in_sizes[2] / 16;
    const int E_s  = in_sizes[3];
    const int E_n  = in_sizes[5];

    char* ws = (char*)d_ws;
    int* cur_s = (int*)ws;              ws += (size_t)n_ag * 4;
    int* cur_n = (int*)ws;              ws += (size_t)n_ag * 4;
    int* csr_s = (int*)ws;              ws += (size_t)E_s * 4;
    int* csr_n = (int*)ws;              ws += (size_t)E_n * 4;
    unsigned short* xcat = (unsigned short*)ws;  ws += (size_t)n_ag * 512 * 2;
    unsigned short* Wt   = (unsigned short*)ws;  // [256][512] bf16

    hipMemsetAsync(cur_s, 0, (size_t)n_ag * 8, stream);  // cur_s, cur_n contiguous

    int gE = (E_s + E_n + 255) / 256;
    k_hist_wt<<<gE, 256, 0, stream>>>(seen_dst, E_s, near_dst, E_n, cur_s, cur_n, W_a, Wt);
    k_scan2<<<2, 1024, 0, stream>>>(cur_s, n_ag, cur_n, n_ag);
    k_scatter<<<gE, 256, 0, stream>>>(seen_src, seen_dst, E_s, near_src, near_dst, E_n,
                                      cur_s, cur_n, csr_s, csr_n);

    int gN = (n_ag + 15) / 16;   // 16 nodes per block (4 waves x 4 nodes)
    k_gat<<<2 * gN, 256, 0, stream>>>(
        x_gt,  cur_s, csr_s, Ws_s, bs_s, Wd_s, bd_s, at_s, Wr_s, br_s,
        x_ubs, cur_n, csr_n, Ws_n, bs_n, Wd_n, bd_n, at_n, Wr_n, br_n,
        x_ag, xcat, n_ag, gN);

    k_mlp<<<(n_ag + 15) / 16, 256, 0, stream>>>(xcat, Wt, b_a, (float*)d_out, n_ag);
}

// Round 3
// 314.444 us; speedup vs baseline: 1.0809x; 1.0676x over previous
//
#include <hip/hip_runtime.h>
#include <math.h>

#define NEG 0.2f

typedef short bf16x8 __attribute__((ext_vector_type(8)));
typedef float f32x4  __attribute__((ext_vector_type(4)));
typedef float f32x2  __attribute__((ext_vector_type(2)));

// ---------------------------------------------------------------------------
// helpers
// ---------------------------------------------------------------------------
static __device__ __forceinline__ f32x2 pkfma(f32x2 a, f32x2 b, f32x2 c) {
    return __builtin_elementwise_fma(a, b, c);   // -> v_pk_fma_f32
}
static __device__ __forceinline__ f32x2 splat2(float x) { return (f32x2){x, x}; }

static __device__ __forceinline__ unsigned short f2bf(float f) {   // RNE, finite
    unsigned int x = __float_as_uint(f);
    unsigned int r = (x + 0x7FFFu + ((x >> 16) & 1u)) >> 16;
    return (unsigned short)r;
}
static __device__ __forceinline__ float rlane(float v, int l) {
    return __int_as_float(__builtin_amdgcn_readlane(__float_as_int(v), l));
}

// Sum across each 16-lane DPP row (head h = lanes 16h..16h+15).
#define DPP_ADD(x, ctrl) \
    ((x) + __int_as_float(__builtin_amdgcn_update_dpp( \
        __float_as_int(x), __float_as_int(x), (ctrl), 0xF, 0xF, true)))
static __device__ __forceinline__ float rowsum16(float v) {
    v = DPP_ADD(v, 0xB1);   // quad_perm xor1
    v = DPP_ADD(v, 0x4E);   // quad_perm xor2
    v = DPP_ADD(v, 0x141);  // row_half_mirror
    v = DPP_ADD(v, 0x140);  // row_mirror
    return v;
}

// ---------------------------------------------------------------------------
// CSR build (separate dispatches; cooperative grid.sync was ~120us/sync, R7)
// ---------------------------------------------------------------------------
__global__ void k_hist_wt(const int* __restrict__ dst_s, int Es,
                          const int* __restrict__ dst_n, int En,
                          int* __restrict__ deg_s, int* __restrict__ deg_n,
                          const float* __restrict__ W, unsigned short* __restrict__ Wt) {
    int i = blockIdx.x * 256 + threadIdx.x;
    if (i < Es) atomicAdd(&deg_s[dst_s[i]], 1);
    int j = i - Es;
    if (j >= 0 && j < En) atomicAdd(&deg_n[dst_n[j]], 1);
    if (i < 512 * 256) {                 // W[512][256] f32 -> Wt[256][512] bf16
        int k = i >> 8, n = i & 255;
        Wt[(size_t)n * 512 + k] = f2bf(W[i]);
    }
}

__global__ __launch_bounds__(1024) void k_scan2(int* a, int na, int* b, int nb) {
    int* p = (blockIdx.x == 0) ? a : b;
    int n  = (blockIdx.x == 0) ? na : nb;
    __shared__ int sums[1024];
    int t = threadIdx.x;
    int C = (n + 1023) >> 10;
    int base = t * C;
    int s = 0;
    for (int j = 0; j < C; ++j) { int i = base + j; if (i < n) s += p[i]; }
    sums[t] = s;
    __syncthreads();
    for (int off = 1; off < 1024; off <<= 1) {
        int v = (t >= off) ? sums[t - off] : 0;
        __syncthreads();
        sums[t] += v;
        __syncthreads();
    }
    int run = (t == 0) ? 0 : sums[t - 1];
    for (int j = 0; j < C; ++j) {
        int i = base + j;
        if (i < n) { int v = p[i]; p[i] = run; run += v; }
    }
}

__global__ void k_scatter(const int* __restrict__ src_s, const int* __restrict__ dst_s, int Es,
                          const int* __restrict__ src_n, const int* __restrict__ dst_n, int En,
                          int* __restrict__ cur_s, int* __restrict__ cur_n,
                          int* __restrict__ csr_s, int* __restrict__ csr_n) {
    int i = blockIdx.x * 256 + threadIdx.x;
    if (i < Es) {
        int pos = atomicAdd(&cur_s[dst_s[i]], 1);
        csr_s[pos] = src_s[i];
    }
    int j = i - Es;
    if (j >= 0 && j < En) {
        int pos = atomicAdd(&cur_n[dst_n[j]], 1);
        csr_n[pos] = src_n[j];
    }
}

// ---------------------------------------------------------------------------
// GATv2, both layers fused by contiguous block ranges (block < gNs -> seen).
// R16 = R13 skeleton (static 4-rep unroll, no dynamic selects -- R15's flat
// stream added ~50 VALU/chunk of scheduling overhead and regressed 36%)
// + R14's branch-free padded chunk body (clamped edge idx + cndmask on p;
//   proven: R14 ran 80.8us even while paying for a bad 61MB gather)
// + NEW: first/second-chunk csr indices and first-chunk x rows of ALL 4 reps
//   hoisted into the prologue, in flight under the ~400-instr fd/fr pass.
//   Kills the 4x per-rep cold pipeline restart (pfx->idx->x, ~900cy each)
//   at zero steady-state instruction cost (rep stays a compile-time const).
// x_gt/x_ubs are 3.8MB total -> L2-resident; in-register fs recompute beats
// any precomputed-table gather (R14: 107MB HBM fetch, L3 misses).
// ---------------------------------------------------------------------------
__global__ __launch_bounds__(256) void k_gat(
    const float* __restrict__ xsrc_s, const int* __restrict__ pfx_s, const int* __restrict__ csr_s,
    const float* __restrict__ Ws_s, const float* __restrict__ bs_s,
    const float* __restrict__ Wd_s, const float* __restrict__ bd_s,
    const float* __restrict__ at_s,
    const float* __restrict__ Wr_s, const float* __restrict__ br_s,
    const float* __restrict__ xsrc_n, const int* __restrict__ pfx_n, const int* __restrict__ csr_n,
    const float* __restrict__ Ws_n, const float* __restrict__ bs_n,
    const float* __restrict__ Wd_n, const float* __restrict__ bd_n,
    const float* __restrict__ at_n,
    const float* __restrict__ Wr_n, const float* __restrict__ br_n,
    const float* __restrict__ x_ag,
    unsigned short* __restrict__ xcat, int n_dst, int gNs)
{
    const bool seen = (int)blockIdx.x < gNs;
    const float* x_src = seen ? xsrc_s : xsrc_n;
    const int*   pfx   = seen ? pfx_s  : pfx_n;
    const int*   csr   = seen ? csr_s  : csr_n;
    const float* Ws    = seen ? Ws_s   : Ws_n;
    const float* bs    = seen ? bs_s   : bs_n;
    const float* Wd    = seen ? Wd_s   : Wd_n;
    const float* bd    = seen ? bd_s   : bd_n;
    const float* at    = seen ? at_s   : at_n;
    const float* Wr    = seen ? Wr_s   : Wr_n;
    const float* br    = seen ? br_s   : br_n;
    const int col = seen ? 0 : 256;
    const int blk = seen ? (int)blockIdx.x : (int)blockIdx.x - gNs;

    const int t = threadIdx.x;
    const int wave = t >> 6, lane = t & 63;
    const int d0 = lane * 4;
    const int gs = lane >> 3;   // edge slot 0..7 within chunk
    const int w8 = lane & 7;    // word within the 8-float src row

    // ---- gather the wave's 4 agent rows: lane L = feat (L&15) of node L>>4
    int gnode = blk * 16 + ((lane >> 4) << 2) + wave;
    int gn = (gnode < n_dst) ? gnode : (n_dst - 1);
    float xag = x_ag[(size_t)gn * 16 + (lane & 15)];

    // ---- the 4 nodes' edge ranges
    int e_start[4], e_deg[4];
#pragma unroll
    for (int j = 0; j < 4; ++j) {
        int nd = blk * 16 + j * 4 + wave;
        nd = (nd < n_dst) ? nd : (n_dst - 1);
        int e = pfx[nd];
        int s = nd ? pfx[nd - 1] : 0;
        e_start[j] = s; e_deg[j] = e - s;
    }

    // ---- hoist first/second-chunk csr indices of all reps (wave-uniform
    //      scalar branch per rep; loads issue back-to-back)
    int i0f[4], i1f[4];
#pragma unroll
    for (int j = 0; j < 4; ++j) {
        int dg = e_deg[j];
        if (dg > 0) {
            int e0 = (gs < dg) ? gs : dg - 1;
            int e1 = (8 + gs < dg) ? 8 + gs : dg - 1;
            i0f[j] = csr[e_start[j] + e0];
            i1f[j] = csr[e_start[j] + e1];
        } else { i0f[j] = 0; i1f[j] = 0; }
    }
    // ---- hoist first-chunk x rows (latency hidden by the fd/fr pass below)
    float x0f[4];
#pragma unroll
    for (int j = 0; j < 4; ++j)
        x0f[j] = x_src[(size_t)i0f[j] * 8 + w8];

    // ---- fd/fr for all 4 nodes in ONE pass over the 32 weight rows (packed)
    f32x2 fd01[4], fd23[4], fr01[4], fr23[4];
    {
        float4 bdv = *(const float4*)&bd[d0];
        float4 brv = *(const float4*)&br[d0];
#pragma unroll
        for (int j = 0; j < 4; ++j) {
            fd01[j] = (f32x2){bdv.x, bdv.y}; fd23[j] = (f32x2){bdv.z, bdv.w};
            fr01[j] = (f32x2){brv.x, brv.y}; fr23[j] = (f32x2){brv.z, brv.w};
        }
#pragma unroll
        for (int k = 0; k < 16; ++k) {
            float4 wd = *(const float4*)&Wd[k * 256 + d0];
            float4 wr = *(const float4*)&Wr[k * 256 + d0];
            f32x2 wd01 = {wd.x, wd.y}, wd23 = {wd.z, wd.w};
            f32x2 wr01 = {wr.x, wr.y}, wr23 = {wr.z, wr.w};
#pragma unroll
            for (int j = 0; j < 4; ++j) {
                f32x2 xk = splat2(rlane(xag, j * 16 + k));
                fd01[j] = pkfma(xk, wd01, fd01[j]);
                fd23[j] = pkfma(xk, wd23, fd23[j]);
                fr01[j] = pkfma(xk, wr01, fr01[j]);
                fr23[j] = pkfma(xk, wr23, fr23[j]);
            }
        }
    }

    // ---- wave-lifetime edge-loop constants (packed pairs)
    f32x2 ws01[8], ws23[8];
#pragma unroll
    for (int k = 0; k < 8; ++k) {
        float4 w = *(const float4*)&Ws[k * 256 + d0];
        ws01[k] = (f32x2){w.x, w.y};
        ws23[k] = (f32x2){w.z, w.w};
    }
    f32x2 bs01, bs23, at01, at23;
    {
        float4 b4 = *(const float4*)&bs[d0];
        float4 a4 = *(const float4*)&at[d0];
        bs01 = (f32x2){b4.x, b4.y}; bs23 = (f32x2){b4.z, b4.w};
        at01 = (f32x2){a4.x, a4.y}; at23 = (f32x2){a4.z, a4.w};
    }

#pragma unroll
    for (int rep = 0; rep < 4; ++rep) {
        const int node = blk * 16 + rep * 4 + wave;
        if (node >= n_dst) continue;

        const int start = e_start[rep];
        const int deg   = e_deg[rep];
        const f32x2 fd01r = fd01[rep], fd23r = fd23[rep];

        float l = 0.f;
        f32x2 a01 = {0.f, 0.f}, a23 = {0.f, 0.f};

        if (deg > 0) {
            float r0 = x0f[rep];   // chunk-0 rows: already resident
            int   i1 = i1f[rep];   // chunk-1 indices: already resident

            for (int base = 0; base < deg; base += 8) {
                float r1 = x_src[(size_t)i1 * 8 + w8];
                int e2 = base + 16 + gs; e2 = (e2 < deg) ? e2 : deg - 1;
                int i2 = csr[start + e2];

                // 8 independent branch-free edges (padded slots alias edge
                // deg-1 -> L1 hit; their weight is zeroed by cndmask)
#pragma unroll
                for (int j = 0; j < 8; ++j) {
                    f32x2 x0 = splat2(rlane(r0, j * 8 + 0));
                    f32x2 x1 = splat2(rlane(r0, j * 8 + 1));
                    f32x2 x2 = splat2(rlane(r0, j * 8 + 2));
                    f32x2 x3 = splat2(rlane(r0, j * 8 + 3));
                    f32x2 x4 = splat2(rlane(r0, j * 8 + 4));
                    f32x2 x5 = splat2(rlane(r0, j * 8 + 5));
                    f32x2 x6 = splat2(rlane(r0, j * 8 + 6));
                    f32x2 x7 = splat2(rlane(r0, j * 8 + 7));

                    f32x2 fs01 = bs01, fs23 = bs23;
                    fs01 = pkfma(x0, ws01[0], fs01); fs23 = pkfma(x0, ws23[0], fs23);
                    fs01 = pkfma(x1, ws01[1], fs01); fs23 = pkfma(x1, ws23[1], fs23);
                    fs01 = pkfma(x2, ws01[2], fs01); fs23 = pkfma(x2, ws23[2], fs23);
                    fs01 = pkfma(x3, ws01[3], fs01); fs23 = pkfma(x3, ws23[3], fs23);
                    fs01 = pkfma(x4, ws01[4], fs01); fs23 = pkfma(x4, ws23[4], fs23);
                    fs01 = pkfma(x5, ws01[5], fs01); fs23 = pkfma(x5, ws23[5], fs23);
                    fs01 = pkfma(x6, ws01[6], fs01); fs23 = pkfma(x6, ws23[6], fs23);
                    fs01 = pkfma(x7, ws01[7], fs01); fs23 = pkfma(x7, ws23[7], fs23);

                    // leaky relu of (fs+fd): max(v, 0.2v), packed
                    f32x2 t01 = fs01 + fd01r;
                    f32x2 t23 = fs23 + fd23r;
                    t01 = __builtin_elementwise_max(t01, NEG * t01);
                    t23 = __builtin_elementwise_max(t23, NEG * t23);

                    f32x2 scp = t01 * at01;
                    scp = pkfma(t23, at23, scp);
                    float sc = scp.x + scp.y;
                    sc = rowsum16(sc);

                    float p = __expf(sc);           // no max shift: |sc| bounded
                    p = (base + j < deg) ? p : 0.f; // padded slot -> weight 0
                    l += p;
                    f32x2 pp = splat2(p);
                    a01 = pkfma(pp, fs01, a01);
                    a23 = pkfma(pp, fs23, a23);
                }
                r0 = r1; i1 = i2;
            }
        }

        float inv = (l > 0.f) ? 1.f / l : 0.f;   // zero in-degree -> rst = 0
        ushort4 o;
        o.x = f2bf(fmaxf(fmaf(a01.x, inv, fr01[rep].x), 0.f));
        o.y = f2bf(fmaxf(fmaf(a01.y, inv, fr01[rep].y), 0.f));
        o.z = f2bf(fmaxf(fmaf(a23.x, inv, fr23[rep].x), 0.f));
        o.w = f2bf(fmaxf(fmaf(a23.y, inv, fr23[rep].y), 0.f));
        *(ushort4*)&xcat[(size_t)node * 512 + col + d0] = o;
    }
}

// ---------------------------------------------------------------------------
// out = relu(X[M,512]bf16 @ W[512,256]bf16 + b) via mfma_f32_16x16x32_bf16.
// Block = 4 waves: rows rbase..rbase+15, wave w covers cols 64w..64w+63.
// A/B frags straight from L2 (no LDS). D: col n=lane&15, row m=q*4+reg.
// ---------------------------------------------------------------------------
__global__ __launch_bounds__(256) void k_mlp(
    const unsigned short* __restrict__ X, const unsigned short* __restrict__ Wt,
    const float* __restrict__ b, float* __restrict__ out, int M)
{
    const int t = threadIdx.x;
    const int wave = t >> 6, lane = t & 63;
    const int m16 = lane & 15, q = lane >> 4;
    const int rbase = blockIdx.x * 16;
    const int nbase = wave * 64;

    int rowa = rbase + m16; if (rowa >= M) rowa = M - 1;
    const unsigned short* xp = X + (size_t)rowa * 512 + q * 8;
    const unsigned short* w0 = Wt + (size_t)(nbase + m16) * 512 + q * 8;
    const unsigned short* w1 = w0 + 16 * 512;
    const unsigned short* w2 = w0 + 32 * 512;
    const unsigned short* w3 = w0 + 48 * 512;

    f32x4 ac0 = {0.f, 0.f, 0.f, 0.f}, ac1 = ac0, ac2 = ac0, ac3 = ac0;

#pragma unroll
    for (int k0 = 0; k0 < 512; k0 += 32) {
        bf16x8 a  = *(const bf16x8*)(xp + k0);
        bf16x8 b0 = *(const bf16x8*)(w0 + k0);
        bf16x8 b1 = *(const bf16x8*)(w1 + k0);
        bf16x8 b2 = *(const bf16x8*)(w2 + k0);
        bf16x8 b3 = *(const bf16x8*)(w3 + k0);
        ac0 = __builtin_amdgcn_mfma_f32_16x16x32_bf16(a, b0, ac0, 0, 0, 0);
        ac1 = __builtin_amdgcn_mfma_f32_16x16x32_bf16(a, b1, ac1, 0, 0, 0);
        ac2 = __builtin_amdgcn_mfma_f32_16x16x32_bf16(a, b2, ac2, 0, 0, 0);
        ac3 = __builtin_amdgcn_mfma_f32_16x16x32_bf16(a, b3, ac3, 0, 0, 0);
    }

#define EPI(AC, J) { \
        int coln = nbase + (J) * 16 + m16; \
        float bias = b[coln]; \
        _Pragma("unroll") \
        for (int r = 0; r < 4; ++r) { \
            int orow = rbase + q * 4 + r; \
            if (orow < M) \
                out[(size_t)orow * 256 + coln] = fmaxf(AC[r] + bias, 0.f); \
        } }
    EPI(ac0, 0) EPI(ac1, 1) EPI(ac2, 2) EPI(ac3, 3)
#undef EPI
}

// ---------------------------------------------------------------------------
extern "C" void kernel_launch(void* const* d_in, const int* in_sizes, int n_in,
                              void* d_out, int out_size, void* d_ws, size_t ws_size,
                              hipStream_t stream) {
    const float* x_gt   = (const float*)d_in[0];
    const float* x_ubs  = (const float*)d_in[1];
    const float* x_ag   = (const float*)d_in[2];
    const int* seen_src = (const int*)d_in[3];
    const int* seen_dst = (const int*)d_in[4];
    const int* near_src = (const int*)d_in[5];
    const int* near_dst = (const int*)d_in[6];
    const float* Ws_s = (const float*)d_in[7];  const float* bs_s = (const float*)d_in[8];
    const float* Wd_s = (const float*)d_in[9];  const float* bd_s = (const float*)d_in[10];
    const float* at_s = (const float*)d_in[11];
    const float* Wr_s = (const float*)d_in[12]; const float* br_s = (const float*)d_in[13];
    const float* Ws_n = (const float*)d_in[14]; const float* bs_n = (const float*)d_in[15];
    const float* Wd_n = (const float*)d_in[16]; const float* bd_n = (const float*)d_in[17];
    const float* at_n = (const float*)d_in[18];
    const float* Wr_n = (const float*)d_in[19]; const float* br_n = (const float*)d_in[20];
    const float* W_a  = (const float*)d_in[21]; const float* b_a  = (const float*)d_in[22];

    const int n_ag = in_sizes[2] / 16;
    const int E_s  = in_sizes[3];
    const int E_n  = in_sizes[5];

    char* ws = (char*)d_ws;
    int* cur_s = (int*)ws;              ws += (size_t)n_ag * 4;
    int* cur_n = (int*)ws;              ws += (size_t)n_ag * 4;
    int* csr_s = (int*)ws;              ws += (size_t)E_s * 4;
    int* csr_n = (int*)ws;              ws += (size_t)E_n * 4;
    unsigned short* xcat = (unsigned short*)ws;  ws += (size_t)n_ag * 512 * 2;
    unsigned short* Wt   = (unsigned short*)ws;  // [256][512] bf16

    hipMemsetAsync(cur_s, 0, (size_t)n_ag * 8, stream);  // cur_s, cur_n contiguous

    int gE = (E_s + E_n + 255) / 256;
    k_hist_wt<<<gE, 256, 0, stream>>>(seen_dst, E_s, near_dst, E_n, cur_s, cur_n, W_a, Wt);
    k_scan2<<<2, 1024, 0, stream>>>(cur_s, n_ag, cur_n, n_ag);
    k_scatter<<<gE, 256, 0, stream>>>(seen_src, seen_dst, E_s, near_src, near_dst, E_n,
                                      cur_s, cur_n, csr_s, csr_n);

    int gN = (n_ag + 15) / 16;   // 16 nodes per block (4 waves x 4 nodes)
    k_gat<<<2 * gN, 256, 0, stream>>>(
        x_gt,  cur_s, csr_s, Ws_s, bs_s, Wd_s, bd_s, at_s, Wr_s, br_s,
        x_ubs, cur_n, csr_n, Ws_n, bs_n, Wd_n, bd_n, at_n, Wr_n, br_n,
        x_ag, xcat, n_ag, gN);

    k_mlp<<<(n_ag + 15) / 16, 256, 0, stream>>>(xcat, Wt, b_a, (float*)d_out, n_ag);
}

// Round 5
// 311.054 us; speedup vs baseline: 1.0927x; 1.0109x over previous
//
#include <hip/hip_runtime.h>
#include <math.h>

#define NEG 0.2f
#define LDSW 520   // LDS row stride in shorts (512 + 8 pad -> banks spread 4/row)

typedef short bf16x8 __attribute__((ext_vector_type(8)));
typedef float f32x4  __attribute__((ext_vector_type(4)));
typedef float f32x2  __attribute__((ext_vector_type(2)));

// ---------------------------------------------------------------------------
// helpers
// ---------------------------------------------------------------------------
static __device__ __forceinline__ f32x2 pkfma(f32x2 a, f32x2 b, f32x2 c) {
    return __builtin_elementwise_fma(a, b, c);   // -> v_pk_fma_f32
}
static __device__ __forceinline__ f32x2 splat2(float x) { return (f32x2){x, x}; }

static __device__ __forceinline__ unsigned short f2bf(float f) {   // RNE, finite
    unsigned int x = __float_as_uint(f);
    unsigned int r = (x + 0x7FFFu + ((x >> 16) & 1u)) >> 16;
    return (unsigned short)r;
}
static __device__ __forceinline__ float rlane(float v, int l) {
    return __int_as_float(__builtin_amdgcn_readlane(__float_as_int(v), l));
}

// Sum across each 16-lane DPP row (head h = lanes 16h..16h+15).
#define DPP_ADD(x, ctrl) \
    ((x) + __int_as_float(__builtin_amdgcn_update_dpp( \
        __float_as_int(x), __float_as_int(x), (ctrl), 0xF, 0xF, true)))
static __device__ __forceinline__ float rowsum16(float v) {
    v = DPP_ADD(v, 0xB1);   // quad_perm xor1
    v = DPP_ADD(v, 0x4E);   // quad_perm xor2
    v = DPP_ADD(v, 0x141);  // row_half_mirror
    v = DPP_ADD(v, 0x140);  // row_mirror
    return v;
}

// ---------------------------------------------------------------------------
// CSR build (separate dispatches; cooperative grid.sync was ~120us/sync, R7)
// ---------------------------------------------------------------------------
__global__ void k_hist_wt(const int* __restrict__ dst_s, int Es,
                          const int* __restrict__ dst_n, int En,
                          int* __restrict__ deg_s, int* __restrict__ deg_n,
                          const float* __restrict__ W, unsigned short* __restrict__ Wt) {
    int i = blockIdx.x * 256 + threadIdx.x;
    if (i < Es) atomicAdd(&deg_s[dst_s[i]], 1);
    int j = i - Es;
    if (j >= 0 && j < En) atomicAdd(&deg_n[dst_n[j]], 1);
    if (i < 512 * 256) {                 // W[512][256] f32 -> Wt[256][512] bf16
        int k = i >> 8, n = i & 255;
        Wt[(size_t)n * 512 + k] = f2bf(W[i]);
    }
}

__global__ __launch_bounds__(1024) void k_scan2(int* a, int na, int* b, int nb) {
    int* p = (blockIdx.x == 0) ? a : b;
    int n  = (blockIdx.x == 0) ? na : nb;
    __shared__ int sums[1024];
    int t = threadIdx.x;
    int C = (n + 1023) >> 10;
    int base = t * C;
    int s = 0;
    for (int j = 0; j < C; ++j) { int i = base + j; if (i < n) s += p[i]; }
    sums[t] = s;
    __syncthreads();
    for (int off = 1; off < 1024; off <<= 1) {
        int v = (t >= off) ? sums[t - off] : 0;
        __syncthreads();
        sums[t] += v;
        __syncthreads();
    }
    int run = (t == 0) ? 0 : sums[t - 1];
    for (int j = 0; j < C; ++j) {
        int i = base + j;
        if (i < n) { int v = p[i]; p[i] = run; run += v; }
    }
}

__global__ void k_scatter(const int* __restrict__ src_s, const int* __restrict__ dst_s, int Es,
                          const int* __restrict__ src_n, const int* __restrict__ dst_n, int En,
                          int* __restrict__ cur_s, int* __restrict__ cur_n,
                          int* __restrict__ csr_s, int* __restrict__ csr_n) {
    int i = blockIdx.x * 256 + threadIdx.x;
    if (i < Es) {
        int pos = atomicAdd(&cur_s[dst_s[i]], 1);
        csr_s[pos] = src_s[i];
    }
    int j = i - Es;
    if (j >= 0 && j < En) {
        int pos = atomicAdd(&cur_n[dst_n[j]], 1);
        csr_n[pos] = src_n[j];
    }
}

// ---------------------------------------------------------------------------
// One GATv2 layer for one wave's 2 dst nodes; results -> LDS (bf16 x4/lane).
// Full chunks of 8 edges run UNGUARDED (no padding, no cndmask, 8 independent
// edges the scheduler can interleave); only the tail chunk uses R13's
// wave-uniform per-edge branch. R16 post-mortem: padded branch-free chunks
// cost +33% edge bodies (63 vs 49.6 us-equiv VALU) -- worse than branches.
// ---------------------------------------------------------------------------
#define EDGE_BODY { \
    f32x2 x0 = splat2(rlane(r0, j * 8 + 0)); \
    f32x2 x1 = splat2(rlane(r0, j * 8 + 1)); \
    f32x2 x2 = splat2(rlane(r0, j * 8 + 2)); \
    f32x2 x3 = splat2(rlane(r0, j * 8 + 3)); \
    f32x2 x4 = splat2(rlane(r0, j * 8 + 4)); \
    f32x2 x5 = splat2(rlane(r0, j * 8 + 5)); \
    f32x2 x6 = splat2(rlane(r0, j * 8 + 6)); \
    f32x2 x7 = splat2(rlane(r0, j * 8 + 7)); \
    f32x2 fs01 = bs01, fs23 = bs23; \
    fs01 = pkfma(x0, ws01[0], fs01); fs23 = pkfma(x0, ws23[0], fs23); \
    fs01 = pkfma(x1, ws01[1], fs01); fs23 = pkfma(x1, ws23[1], fs23); \
    fs01 = pkfma(x2, ws01[2], fs01); fs23 = pkfma(x2, ws23[2], fs23); \
    fs01 = pkfma(x3, ws01[3], fs01); fs23 = pkfma(x3, ws23[3], fs23); \
    fs01 = pkfma(x4, ws01[4], fs01); fs23 = pkfma(x4, ws23[4], fs23); \
    fs01 = pkfma(x5, ws01[5], fs01); fs23 = pkfma(x5, ws23[5], fs23); \
    fs01 = pkfma(x6, ws01[6], fs01); fs23 = pkfma(x6, ws23[6], fs23); \
    fs01 = pkfma(x7, ws01[7], fs01); fs23 = pkfma(x7, ws23[7], fs23); \
    f32x2 t01 = fs01 + fd01r; \
    f32x2 t23 = fs23 + fd23r; \
    t01 = __builtin_elementwise_max(t01, NEG * t01); \
    t23 = __builtin_elementwise_max(t23, NEG * t23); \
    f32x2 scp = t01 * at01; \
    scp = pkfma(t23, at23, scp); \
    float sc = scp.x + scp.y; \
    sc = rowsum16(sc); \
    float p = __expf(sc);   /* no max shift: |sc| bounded, verified R6-R16 */ \
    l += p; \
    f32x2 pp = splat2(p); \
    a01 = pkfma(pp, fs01, a01); \
    a23 = pkfma(pp, fs23, a23); }

static __device__ __forceinline__ void gat_layer(
    const float* __restrict__ x_src, const int* __restrict__ csr,
    const float* __restrict__ Ws, const float* __restrict__ bs,
    const float* __restrict__ Wd, const float* __restrict__ bd,
    const float* __restrict__ at,
    const float* __restrict__ Wr, const float* __restrict__ br,
    float xag, int lane,
    const int* st, const int* dg,          // [2] wave-uniform
    const int* i1pre, const float* x0pre,  // [2] preloaded chunk1-idx / chunk0-rows
    unsigned short* __restrict__ ldsout)   // row0 at +0, row1 at +LDSW (shorts)
{
    const int d0 = lane * 4;
    const int gs = lane >> 3;   // edge slot 0..7 within chunk
    const int w8 = lane & 7;    // word within the 8-float src row

    // ---- fd/fr for the wave's 2 nodes in one pass over the 32 weight rows
    f32x2 fd01[2], fd23[2], fr01[2], fr23[2];
    {
        float4 bdv = *(const float4*)&bd[d0];
        float4 brv = *(const float4*)&br[d0];
#pragma unroll
        for (int j = 0; j < 2; ++j) {
            fd01[j] = (f32x2){bdv.x, bdv.y}; fd23[j] = (f32x2){bdv.z, bdv.w};
            fr01[j] = (f32x2){brv.x, brv.y}; fr23[j] = (f32x2){brv.z, brv.w};
        }
#pragma unroll
        for (int k = 0; k < 16; ++k) {
            float4 wd = *(const float4*)&Wd[k * 256 + d0];
            float4 wr = *(const float4*)&Wr[k * 256 + d0];
            f32x2 wd01 = {wd.x, wd.y}, wd23 = {wd.z, wd.w};
            f32x2 wr01 = {wr.x, wr.y}, wr23 = {wr.z, wr.w};
#pragma unroll
            for (int j = 0; j < 2; ++j) {
                f32x2 xk = splat2(rlane(xag, j * 16 + k));
                fd01[j] = pkfma(xk, wd01, fd01[j]);
                fd23[j] = pkfma(xk, wd23, fd23[j]);
                fr01[j] = pkfma(xk, wr01, fr01[j]);
                fr23[j] = pkfma(xk, wr23, fr23[j]);
            }
        }
    }

    // ---- edge-loop constants (packed pairs)
    f32x2 ws01[8], ws23[8];
#pragma unroll
    for (int k = 0; k < 8; ++k) {
        float4 w = *(const float4*)&Ws[k * 256 + d0];
        ws01[k] = (f32x2){w.x, w.y};
        ws23[k] = (f32x2){w.z, w.w};
    }
    f32x2 bs01, bs23, at01, at23;
    {
        float4 b4 = *(const float4*)&bs[d0];
        float4 a4 = *(const float4*)&at[d0];
        bs01 = (f32x2){b4.x, b4.y}; bs23 = (f32x2){b4.z, b4.w};
        at01 = (f32x2){a4.x, a4.y}; at23 = (f32x2){a4.z, a4.w};
    }

#pragma unroll
    for (int rep = 0; rep < 2; ++rep) {
        const int start = st[rep];
        const int deg   = dg[rep];
        const f32x2 fd01r = fd01[rep], fd23r = fd23[rep];

        float l = 0.f;
        f32x2 a01 = {0.f, 0.f}, a23 = {0.f, 0.f};

        if (deg > 0) {
            float r0 = x0pre[rep];         // chunk-0 rows already resident
            int   i1 = i1pre[rep];         // chunk-1 indices already resident
            const int nfull = deg >> 3, tail = deg & 7;

            for (int c = 0; c < nfull; ++c) {
                float r1 = x_src[(size_t)i1 * 8 + w8];
                int e2 = c * 8 + 16 + gs; e2 = (e2 < deg) ? e2 : deg - 1;
                int i2 = csr[start + e2];
#pragma unroll
                for (int j = 0; j < 8; ++j) EDGE_BODY   // unguarded full chunk
                r0 = r1; i1 = i2;
            }
            if (tail) {
#pragma unroll
                for (int j = 0; j < 8; ++j)
                    if (j < tail) EDGE_BODY              // uniform scalar branch
            }
        }

        float inv = (l > 0.f) ? 1.f / l : 0.f;   // zero in-degree -> rst = 0
        ushort4 o;
        o.x = f2bf(fmaxf(fmaf(a01.x, inv, fr01[rep].x), 0.f));
        o.y = f2bf(fmaxf(fmaf(a01.y, inv, fr01[rep].y), 0.f));
        o.z = f2bf(fmaxf(fmaf(a23.x, inv, fr23[rep].x), 0.f));
        o.w = f2bf(fmaxf(fmaf(a23.y, inv, fr23[rep].y), 0.f));
        *(ushort4*)(ldsout + rep * LDSW) = o;
    }
}

// ---------------------------------------------------------------------------
// Fused GAT(seen)+GAT(near)+MLP. Block = 512 thr (8 waves), 16 nodes/block.
// Wave w handles nodes nb+2w, nb+2w+1 for BOTH layers sequentially (balanced:
// every wave gets ~2x16 + 2x8 = 48 edges), writing the 16x512 xcat tile to
// LDS only. Then one barrier and an in-block MFMA MLP (wave w covers 32 cols)
// reading A from LDS. Removes the k_mlp dispatch, its grid ramp, and the
// 40MB xcat HBM round-trip.
// NOTE R18: __launch_bounds__ min-waves hint removed -- (512,4) capped the
// allocator at 128 VGPR and risked scratch spills (new resource request vs
// R16; suspect in the container failure). Allocator now free to pick.
// ---------------------------------------------------------------------------
__global__ __launch_bounds__(512) void k_gatmlp(
    const float* __restrict__ xsrc_s, const int* __restrict__ pfx_s, const int* __restrict__ csr_s,
    const float* __restrict__ Ws_s, const float* __restrict__ bs_s,
    const float* __restrict__ Wd_s, const float* __restrict__ bd_s,
    const float* __restrict__ at_s,
    const float* __restrict__ Wr_s, const float* __restrict__ br_s,
    const float* __restrict__ xsrc_n, const int* __restrict__ pfx_n, const int* __restrict__ csr_n,
    const float* __restrict__ Ws_n, const float* __restrict__ bs_n,
    const float* __restrict__ Wd_n, const float* __restrict__ bd_n,
    const float* __restrict__ at_n,
    const float* __restrict__ Wr_n, const float* __restrict__ br_n,
    const float* __restrict__ x_ag,
    const unsigned short* __restrict__ Wt, const float* __restrict__ bmlp,
    float* __restrict__ out, int n_dst)
{
    __shared__ unsigned short xt[16 * LDSW];   // 16.6 KB

    const int t = threadIdx.x;
    const int wave = t >> 6, lane = t & 63;
    const int gs = lane >> 3, w8 = lane & 7;
    const int nb = (int)blockIdx.x * 16;

    int nd0 = nb + wave * 2;     nd0 = (nd0 < n_dst) ? nd0 : n_dst - 1;
    int nd1 = nb + wave * 2 + 1; nd1 = (nd1 < n_dst) ? nd1 : n_dst - 1;

    // lane L = feat (L&15) of node ((L>>4)&1): groups 0,2->node0; 1,3->node1
    float xag = x_ag[(size_t)(((lane >> 4) & 1) ? nd1 : nd0) * 16 + (lane & 15)];

    // ---- edge ranges of the 4 tasks (pfx is INCLUSIVE prefix after scan)
    int stS[2], dgS[2], stN[2], dgN[2];
#pragma unroll
    for (int j = 0; j < 2; ++j) {
        int n = j ? nd1 : nd0;
        int eS = pfx_s[n], sS = n ? pfx_s[n - 1] : 0;
        int eN = pfx_n[n], sN = n ? pfx_n[n - 1] : 0;
        stS[j] = sS; dgS[j] = eS - sS;
        stN[j] = sN; dgN[j] = eN - sN;
    }

    // ---- phase-A preloads (latency hidden under phase-A fd/fr weight pass)
    int i0S[2], i1S[2]; float x0S[2];
#pragma unroll
    for (int j = 0; j < 2; ++j) {
        int dgj = dgS[j];
        if (dgj > 0) {
            int e0 = (gs < dgj) ? gs : dgj - 1;
            int e1 = (8 + gs < dgj) ? 8 + gs : dgj - 1;
            i0S[j] = csr_s[stS[j] + e0];
            i1S[j] = csr_s[stS[j] + e1];
        } else { i0S[j] = 0; i1S[j] = 0; }
    }
#pragma unroll
    for (int j = 0; j < 2; ++j)
        x0S[j] = xsrc_s[(size_t)i0S[j] * 8 + w8];

    unsigned short* ldsA = &xt[(wave * 2) * LDSW + lane * 4];
    gat_layer(xsrc_s, csr_s, Ws_s, bs_s, Wd_s, bd_s, at_s, Wr_s, br_s,
              xag, lane, stS, dgS, i1S, x0S, ldsA);

    // ---- phase-B preloads (issued before phase-B weight pass)
    int i0N[2], i1N[2]; float x0N[2];
#pragma unroll
    for (int j = 0; j < 2; ++j) {
        int dgj = dgN[j];
        if (dgj > 0) {
            int e0 = (gs < dgj) ? gs : dgj - 1;
            int e1 = (8 + gs < dgj) ? 8 + gs : dgj - 1;
            i0N[j] = csr_n[stN[j] + e0];
            i1N[j] = csr_n[stN[j] + e1];
        } else { i0N[j] = 0; i1N[j] = 0; }
    }
#pragma unroll
    for (int j = 0; j < 2; ++j)
        x0N[j] = xsrc_n[(size_t)i0N[j] * 8 + w8];

    gat_layer(xsrc_n, csr_n, Ws_n, bs_n, Wd_n, bd_n, at_n, Wr_n, br_n,
              xag, lane, stN, dgN, i1N, x0N, ldsA + 256);

    __syncthreads();

    // ---- MLP: out[16 rows, 256 cols] = relu(xt @ Wt^T + b), wave w: 32 cols
    const int m16 = lane & 15, q = lane >> 4;
    const unsigned short* w0 = Wt + (size_t)(wave * 32 + m16) * 512 + q * 8;
    const unsigned short* w1 = w0 + 16 * 512;
    const unsigned short* ap = &xt[m16 * LDSW + q * 8];

    f32x4 ac0 = {0.f, 0.f, 0.f, 0.f}, ac1 = ac0;
#pragma unroll
    for (int k0 = 0; k0 < 512; k0 += 32) {
        bf16x8 a  = *(const bf16x8*)(ap + k0);
        bf16x8 b0 = *(const bf16x8*)(w0 + k0);
        bf16x8 b1 = *(const bf16x8*)(w1 + k0);
        ac0 = __builtin_amdgcn_mfma_f32_16x16x32_bf16(a, b0, ac0, 0, 0, 0);
        ac1 = __builtin_amdgcn_mfma_f32_16x16x32_bf16(a, b1, ac1, 0, 0, 0);
    }

#define EPI(AC, J) { \
        int coln = wave * 32 + (J) * 16 + m16; \
        float bv = bmlp[coln]; \
        _Pragma("unroll") \
        for (int r = 0; r < 4; ++r) { \
            int orow = nb + q * 4 + r; \
            if (orow < n_dst) \
                out[(size_t)orow * 256 + coln] = fmaxf(AC[r] + bv, 0.f); \
        } }
    EPI(ac0, 0) EPI(ac1, 1)
#undef EPI
}

// ---------------------------------------------------------------------------
extern "C" void kernel_launch(void* const* d_in, const int* in_sizes, int n_in,
                              void* d_out, int out_size, void* d_ws, size_t ws_size,
                              hipStream_t stream) {
    const float* x_gt   = (const float*)d_in[0];
    const float* x_ubs  = (const float*)d_in[1];
    const float* x_ag   = (const float*)d_in[2];
    const int* seen_src = (const int*)d_in[3];
    const int* seen_dst = (const int*)d_in[4];
    const int* near_src = (const int*)d_in[5];
    const int* near_dst = (const int*)d_in[6];
    const float* Ws_s = (const float*)d_in[7];  const float* bs_s = (const float*)d_in[8];
    const float* Wd_s = (const float*)d_in[9];  const float* bd_s = (const float*)d_in[10];
    const float* at_s = (const float*)d_in[11];
    const float* Wr_s = (const float*)d_in[12]; const float* br_s = (const float*)d_in[13];
    const float* Ws_n = (const float*)d_in[14]; const float* bs_n = (const float*)d_in[15];
    const float* Wd_n = (const float*)d_in[16]; const float* bd_n = (const float*)d_in[17];
    const float* at_n = (const float*)d_in[18];
    const float* Wr_n = (const float*)d_in[19]; const float* br_n = (const float*)d_in[20];
    const float* W_a  = (const float*)d_in[21]; const float* b_a  = (const float*)d_in[22];

    const int n_ag = in_sizes[2] / 16;
    const int E_s  = in_sizes[3];
    const int E_n  = in_sizes[5];

    char* ws = (char*)d_ws;
    int* cur_s = (int*)ws;              ws += (size_t)n_ag * 4;
    int* cur_n = (int*)ws;              ws += (size_t)n_ag * 4;
    int* csr_s = (int*)ws;              ws += (size_t)E_s * 4;
    int* csr_n = (int*)ws;              ws += (size_t)E_n * 4;
    unsigned short* Wt   = (unsigned short*)ws;  // [256][512] bf16

    hipMemsetAsync(cur_s, 0, (size_t)n_ag * 8, stream);  // cur_s, cur_n contiguous

    int gE = (E_s + E_n + 255) / 256;
    k_hist_wt<<<gE, 256, 0, stream>>>(seen_dst, E_s, near_dst, E_n, cur_s, cur_n, W_a, Wt);
    k_scan2<<<2, 1024, 0, stream>>>(cur_s, n_ag, cur_n, n_ag);
    k_scatter<<<gE, 256, 0, stream>>>(seen_src, seen_dst, E_s, near_src, near_dst, E_n,
                                      cur_s, cur_n, csr_s, csr_n);

    int gN = (n_ag + 15) / 16;   // 16 nodes per block (8 waves x 2 nodes x 2 layers)
    k_gatmlp<<<gN, 512, 0, stream>>>(
        x_gt,  cur_s, csr_s, Ws_s, bs_s, Wd_s, bd_s, at_s, Wr_s, br_s,
        x_ubs, cur_n, csr_n, Ws_n, bs_n, Wd_n, bd_n, at_n, Wr_n, br_n,
        x_ag, Wt, b_a, (float*)d_out, n_ag);
}